// Round 2
// baseline (1730.566 us; speedup 1.0000x reference)
//
#include <hip/hip_runtime.h>

// Problem constants
#define D_  1024
#define H_  1024
#define H2_ 512
#define M_  15
#define B_  8192

typedef __attribute__((ext_vector_type(4))) float f32x4;
typedef __attribute__((ext_vector_type(8))) short short8;

__device__ __forceinline__ unsigned short f2bf(float f) {
  unsigned int u = __float_as_uint(f);
  u += 0x7fffu + ((u >> 16) & 1u);   // round-to-nearest-even
  return (unsigned short)(u >> 16);
}
__device__ __forceinline__ float bf2f(unsigned int h) {
  return __uint_as_float(h << 16);
}
__device__ __forceinline__ float gelu_exact(float x) {
  return 0.5f * x * (1.0f + erff(x * 0.70710678118654752440f));
}

// ---------------- fp32 -> bf16 cast (vectorized) ----------------
__global__ void cast_f32_bf16(const float* __restrict__ in, unsigned short* __restrict__ out, int n4) {
  int i = blockIdx.x * blockDim.x + threadIdx.x;
  if (i >= n4) return;
  float4 v = ((const float4*)in)[i];
  ushort4 o;
  o.x = f2bf(v.x); o.y = f2bf(v.y); o.z = f2bf(v.z); o.w = f2bf(v.w);
  ((ushort4*)out)[i] = o;
}

// ---------------- fp32 [K,N] -> bf16 [N,K] transpose-cast ----------------
__global__ void transpose_cast(const float* __restrict__ in, unsigned short* __restrict__ out,
                               int K, int N) {
  __shared__ float t[32][33];
  const size_t mo = (size_t)blockIdx.z * K * N;
  in  += mo;
  out += mo;
  const int k0 = blockIdx.x * 32, n0 = blockIdx.y * 32;
  const int tx = threadIdx.x, ty = threadIdx.y;
#pragma unroll
  for (int j = 0; j < 32; j += 8)
    t[ty + j][tx] = in[(size_t)(k0 + ty + j) * N + (n0 + tx)];
  __syncthreads();
#pragma unroll
  for (int j = 0; j < 32; j += 8)
    out[(size_t)(n0 + ty + j) * K + (k0 + tx)] = f2bf(t[tx][ty + j]);
}

// ---------------- 128x128 2-phase GEMM (kept for the small attention GEMMs) -----------
template <int EPI>
__launch_bounds__(256, 3)
__global__ void gemm_bt(const unsigned short* __restrict__ A, const unsigned short* __restrict__ Bt,
                        const float* __restrict__ bias, void* __restrict__ Cout,
                        int Mrows, int N, int K,
                        long sA, long sB, long sBias, long sC) {
  __shared__ __align__(16) unsigned short As[128 * 64];
  __shared__ __align__(16) unsigned short Bs[128 * 64];
  const int mz = blockIdx.z;
  A    += (size_t)mz * sA;
  Bt   += (size_t)mz * sB;
  bias += (size_t)mz * sBias;

  const int tid  = threadIdx.x;
  const int w    = tid >> 6;
  const int lane = tid & 63;
  const int row0 = blockIdx.x * 128;
  const int col0 = blockIdx.y * 128;

  f32x4 acc[4][4];
#pragma unroll
  for (int i = 0; i < 4; ++i)
#pragma unroll
    for (int j = 0; j < 4; ++j) acc[i][j] = (f32x4){0.f, 0.f, 0.f, 0.f};

  const int wm = w >> 1, wn = w & 1;
  const int mrow = lane & 15;
  const int kq   = (lane >> 4) << 3;

  for (int k0 = 0; k0 < K; k0 += 64) {
    __syncthreads();
#pragma unroll
    for (int i = 0; i < 4; ++i) {
      const int c  = i * 256 + tid;
      const int m  = c >> 3;
      const int kk = (c & 7) << 3;
      const unsigned short* gA = A  + (size_t)(row0 + m) * K + (k0 + kk);
      const unsigned short* gB = Bt + (size_t)(col0 + m) * K + (k0 + kk);
      const int ldsoff = (i * 256 + w * 64) * 8;
      __builtin_amdgcn_global_load_lds((const __attribute__((address_space(1))) void*)gA,
                                       (__attribute__((address_space(3))) void*)(As + ldsoff),
                                       16, 0, 0);
      __builtin_amdgcn_global_load_lds((const __attribute__((address_space(1))) void*)gB,
                                       (__attribute__((address_space(3))) void*)(Bs + ldsoff),
                                       16, 0, 0);
    }
    __syncthreads();
#pragma unroll
    for (int ki = 0; ki < 64; ki += 32) {
      short8 af[4], bf[4];
#pragma unroll
      for (int f = 0; f < 4; ++f) {
        af[f] = *(const short8*)(As + (wm * 64 + f * 16 + mrow) * 64 + ki + kq);
        bf[f] = *(const short8*)(Bs + (wn * 64 + f * 16 + mrow) * 64 + ki + kq);
      }
#pragma unroll
      for (int fm = 0; fm < 4; ++fm)
#pragma unroll
        for (int fn = 0; fn < 4; ++fn)
          acc[fm][fn] = __builtin_amdgcn_mfma_f32_16x16x32_bf16(af[fm], bf[fn], acc[fm][fn], 0, 0, 0);
    }
  }

  float*          Cf = (float*)Cout          + (size_t)mz * sC;
  unsigned short* Cb = (unsigned short*)Cout + (size_t)mz * sC;
  const int rq = (lane >> 4) << 2;
  const int cl = lane & 15;
#pragma unroll
  for (int fm = 0; fm < 4; ++fm) {
#pragma unroll
    for (int fn = 0; fn < 4; ++fn) {
      const int cc = col0 + wn * 64 + fn * 16 + cl;
      const float bv = bias[cc];
#pragma unroll
      for (int r = 0; r < 4; ++r) {
        const int rr = row0 + wm * 64 + fm * 16 + rq + r;
        float v = acc[fm][fn][r] + bv;
        if (EPI == 2) {
          Cf[(size_t)rr * N + cc] = 1.0f / (1.0f + __expf(-v));
        } else {
          if (EPI == 1) v = gelu_exact(v);
          Cb[(size_t)rr * N + cc] = f2bf(v);
        }
      }
    }
  }
}

// ================= 256x256 8-phase counted-vmcnt GEMM (grouped MLP GEMMs) =================
// 512 threads = 8 waves (2 M x 4 N), per-wave C = 128x64, BK=64, LDS 128KB (2 dbuf).
// LDS row permutation: A rows: swap bits 6,7 (region P = m0-3 rows of both halves -> rho 0..127,
//   Q = m4-7 rows -> rho 128..255). B cols: bit5 -> top (R = n0-1 -> 0..127, S = n2-3 -> 128..255).
// XOR slot swizzle (chunk ^= rho&7) applied on the *global source* during staging (linear LDS
// dest, rule #21) and on the ds_read address -> conflict-free ds_read_b128.
#define BAR()   asm volatile("s_barrier" ::: "memory")
#define LGKM0() asm volatile("s_waitcnt lgkmcnt(0)" ::: "memory")
#define VM6()   asm volatile("s_waitcnt vmcnt(6)" ::: "memory")

#define STG_A(bufi, kt, rho0) do {                                                             \
  _Pragma("unroll")                                                                            \
  for (int j_ = 0; j_ < 2; ++j_) {                                                             \
    const int rho_ = (rho0) + j_ * 64 + (tid >> 3);                                            \
    const int gr_  = (((rho_ >> 6) & 1) << 7) | (((rho_ >> 7) & 1) << 6) | (rho_ & 63);        \
    const unsigned short* g_ = A + (size_t)(row0 + gr_) * K + (size_t)(kt) * 64                \
                                 + (((tid & 7) ^ (rho_ & 7)) << 3);                            \
    __builtin_amdgcn_global_load_lds((const __attribute__((address_space(1))) void*)g_,        \
        (__attribute__((address_space(3))) void*)(&As[bufi][(rho0) * 64 + (j_ * 512 + w6 * 64) * 8]), \
        16, 0, 0);                                                                             \
  }                                                                                            \
} while (0)

#define STG_B(bufi, kt, rho0) do {                                                             \
  _Pragma("unroll")                                                                            \
  for (int j_ = 0; j_ < 2; ++j_) {                                                             \
    const int rho_ = (rho0) + j_ * 64 + (tid >> 3);                                            \
    const int gc_  = (((rho_ >> 5) & 3) << 6) | (((rho_ >> 7) & 1) << 5) | (rho_ & 31);        \
    const unsigned short* g_ = Bt + (size_t)(col0 + gc_) * K + (size_t)(kt) * 64               \
                                  + (((tid & 7) ^ (rho_ & 7)) << 3);                           \
    __builtin_amdgcn_global_load_lds((const __attribute__((address_space(1))) void*)g_,        \
        (__attribute__((address_space(3))) void*)(&Bs[bufi][(rho0) * 64 + (j_ * 512 + w6 * 64) * 8]), \
        16, 0, 0);                                                                             \
  }                                                                                            \
} while (0)

#define LDA4(bufi, hi) do {                                                                    \
  _Pragma("unroll")                                                                            \
  for (int q_ = 0; q_ < 4; ++q_) {                                                             \
    const int rho_ = ((hi) ? 128 : 0) + wm * 64 + q_ * 16 + lrow;                              \
    a[q_][0] = *(const short8*)&As[bufi][rho_ * 64 + ((lk ^ (rho_ & 7)) << 3)];                \
    a[q_][1] = *(const short8*)&As[bufi][rho_ * 64 + (((4 + lk) ^ (rho_ & 7)) << 3)];          \
  }                                                                                            \
} while (0)

#define LDB2(bufi, hi) do {                                                                    \
  _Pragma("unroll")                                                                            \
  for (int q_ = 0; q_ < 2; ++q_) {                                                             \
    const int rho_ = ((hi) ? 128 : 0) + wn * 32 + q_ * 16 + lrow;                              \
    b[(hi) * 2 + q_][0] = *(const short8*)&Bs[bufi][rho_ * 64 + ((lk ^ (rho_ & 7)) << 3)];     \
    b[(hi) * 2 + q_][1] = *(const short8*)&Bs[bufi][rho_ * 64 + (((4 + lk) ^ (rho_ & 7)) << 3)]; \
  }                                                                                            \
} while (0)

#define MMQ(mh, nh) do {                                                                       \
  __builtin_amdgcn_s_setprio(1);                                                               \
  _Pragma("unroll")                                                                            \
  for (int mq_ = 0; mq_ < 4; ++mq_) {                                                          \
    _Pragma("unroll")                                                                          \
    for (int nq_ = 0; nq_ < 2; ++nq_) {                                                        \
      acc[(mh) * 4 + mq_][(nh) * 2 + nq_] = __builtin_amdgcn_mfma_f32_16x16x32_bf16(           \
          a[mq_][0], b[(nh) * 2 + nq_][0], acc[(mh) * 4 + mq_][(nh) * 2 + nq_], 0, 0, 0);      \
      acc[(mh) * 4 + mq_][(nh) * 2 + nq_] = __builtin_amdgcn_mfma_f32_16x16x32_bf16(           \
          a[mq_][1], b[(nh) * 2 + nq_][1], acc[(mh) * 4 + mq_][(nh) * 2 + nq_], 0, 0, 0);      \
    }                                                                                          \
  }                                                                                            \
  __builtin_amdgcn_s_setprio(0);                                                               \
} while (0)

template <int EPI>
__launch_bounds__(512, 2)
__global__ void gemm256(const unsigned short* __restrict__ A, const unsigned short* __restrict__ Bt,
                        const float* __restrict__ bias, void* __restrict__ Cout,
                        int N, int K, long sA, long sB, long sBias, long sC) {
  __shared__ __align__(16) unsigned short As[2][256 * 64];
  __shared__ __align__(16) unsigned short Bs[2][256 * 64];

  // bijective XCD-aware swizzle (all launches have nwg % 8 == 0)
  const int gx = gridDim.x, gy = gridDim.y;
  const int nwg = gx * gy * gridDim.z;
  const int bid = blockIdx.x + gx * (blockIdx.y + gy * blockIdx.z);
  int orig = bid;
  if ((nwg & 7) == 0) {
    const int cpx = nwg >> 3;
    orig = (bid & 7) * cpx + (bid >> 3);
  }
  const int bx = orig % gx;
  const int r1 = orig / gx;
  const int by = r1 % gy;
  const int mz = r1 / gy;

  A    += (size_t)mz * sA;
  Bt   += (size_t)mz * sB;
  bias += (size_t)mz * sBias;

  const int tid  = threadIdx.x;
  const int w6   = tid >> 6;      // wave 0..7
  const int lane = tid & 63;
  const int wm   = w6 >> 2;       // 0..1
  const int wn   = w6 & 3;        // 0..3
  const int lrow = lane & 15;
  const int lk   = lane >> 4;     // 0..3
  const int row0 = bx * 256;
  const int col0 = by * 256;
  const int nt   = K >> 6;        // K-tiles (even: 8 or 16)

  f32x4 acc[8][4];
#pragma unroll
  for (int i = 0; i < 8; ++i)
#pragma unroll
    for (int j = 0; j < 4; ++j) acc[i][j] = (f32x4){0.f, 0.f, 0.f, 0.f};
  short8 a[4][2], b[4][2];

  // prologue: tile0 {A-P, B-R, B-S, A-Q}, tile1 {A-P, B-R, B-S}; wait tile0 (8 oldest)
  STG_A(0, 0, 0); STG_B(0, 0, 0); STG_B(0, 0, 128); STG_A(0, 0, 128);
  STG_A(1, 1, 0); STG_B(1, 1, 0); STG_B(1, 1, 128);
  VM6(); BAR();

#pragma unroll 1
  for (int it = 0; it < (nt >> 1); ++it) {
    const int T  = it * 2;
    const int t2 = (T + 2 < nt) ? T + 2 : nt - 1;   // clamped prefetch (garbage ok, never read)
    const int t3 = (T + 3 < nt) ? T + 3 : nt - 1;
    // ---- tile T from buf0 ----
    // ph1
    LDA4(0, 0); LDB2(0, 0);
    STG_A(1, T + 1, 128);            // A-Q(T+1)
    BAR(); LGKM0();
    MMQ(0, 0);
    BAR();
    // ph2
    LDB2(0, 1);
    STG_A(0, t2, 0);                 // A-P(T+2)
    BAR(); LGKM0();
    MMQ(0, 1);
    BAR();
    // ph3
    LDA4(0, 1);
    STG_B(0, t2, 0);                 // B-R(T+2)
    BAR(); LGKM0();
    MMQ(1, 0);
    BAR();
    // ph4
    STG_B(0, t2, 128);               // B-S(T+2)
    VM6(); BAR();                    // tile T+1 now resident
    MMQ(1, 1);
    BAR();
    // ---- tile T+1 from buf1 ----
    // ph5
    LDA4(1, 0); LDB2(1, 0);
    STG_A(0, t2, 128);               // A-Q(T+2)
    BAR(); LGKM0();
    MMQ(0, 0);
    BAR();
    // ph6
    LDB2(1, 1);
    STG_A(1, t3, 0);                 // A-P(T+3)
    BAR(); LGKM0();
    MMQ(0, 1);
    BAR();
    // ph7
    LDA4(1, 1);
    STG_B(1, t3, 0);                 // B-R(T+3)
    BAR(); LGKM0();
    MMQ(1, 0);
    BAR();
    // ph8
    STG_B(1, t3, 128);               // B-S(T+3)
    VM6(); BAR();                    // tile T+2 now resident
    MMQ(1, 1);
    BAR();
  }
  asm volatile("s_waitcnt vmcnt(0)" ::: "memory");   // drain clamped tail prefetches

  // epilogue: C/D layout col=lane&15, row=(lane>>4)*4+reg
  float*          Cf = (float*)Cout          + (size_t)mz * sC;
  unsigned short* Cb = (unsigned short*)Cout + (size_t)mz * sC;
  const int rq = (lane >> 4) << 2;
  const int cl = lane & 15;
#pragma unroll
  for (int nf = 0; nf < 4; ++nf) {
    const int cc = col0 + wn * 64 + nf * 16 + cl;
    const float bv = bias[cc];
#pragma unroll
    for (int mf = 0; mf < 8; ++mf) {
#pragma unroll
      for (int r = 0; r < 4; ++r) {
        const int rr = row0 + wm * 128 + mf * 16 + rq + r;
        float v = acc[mf][nf][r] + bv;
        if (EPI == 2) {
          Cf[(size_t)rr * N + cc] = 1.0f / (1.0f + __expf(-v));
        } else {
          if (EPI == 1) v = gelu_exact(v);
          Cb[(size_t)rr * N + cc] = f2bf(v);
        }
      }
    }
  }
}

// ---------------- Grouped LayerNorm + exact GELU, rows of length H_ ----------------
__global__ void ln_gelu(const unsigned short* __restrict__ in, const float* __restrict__ g,
                        const float* __restrict__ bb, unsigned short* __restrict__ out) {
  const int m = blockIdx.y;
  in  += (size_t)m * B_ * H_;
  out += (size_t)m * B_ * H_;
  g   += (size_t)m * H_;
  bb  += (size_t)m * H_;
  const int row = blockIdx.x;
  const int tid = threadIdx.x;
  const unsigned short* rp = in + (size_t)row * H_;
  uint2 u = ((const uint2*)rp)[tid];
  float x0 = bf2f(u.x & 0xffffu);
  float x1 = bf2f(u.x >> 16);
  float x2 = bf2f(u.y & 0xffffu);
  float x3 = bf2f(u.y >> 16);

  float s  = x0 + x1 + x2 + x3;
  float s2 = x0 * x0 + x1 * x1 + x2 * x2 + x3 * x3;
#pragma unroll
  for (int o = 32; o > 0; o >>= 1) {
    s  += __shfl_down(s, o);
    s2 += __shfl_down(s2, o);
  }
  __shared__ float red[10];
  const int w = tid >> 6;
  if ((tid & 63) == 0) { red[w] = s; red[4 + w] = s2; }
  __syncthreads();
  if (tid == 0) {
    float ts = red[0] + red[1] + red[2] + red[3];
    float t2 = red[4] + red[5] + red[6] + red[7];
    float mean = ts * (1.0f / H_);
    float var  = t2 * (1.0f / H_) - mean * mean;
    red[8] = mean;
    red[9] = rsqrtf(var + 1e-5f);
  }
  __syncthreads();
  const float mean = red[8], rstd = red[9];
  const int col = tid * 4;
  float y0 = gelu_exact((x0 - mean) * rstd * g[col + 0] + bb[col + 0]);
  float y1 = gelu_exact((x1 - mean) * rstd * g[col + 1] + bb[col + 1]);
  float y2 = gelu_exact((x2 - mean) * rstd * g[col + 2] + bb[col + 2]);
  float y3 = gelu_exact((x3 - mean) * rstd * g[col + 3] + bb[col + 3]);
  ushort4 o;
  o.x = f2bf(y0); o.y = f2bf(y1); o.z = f2bf(y2); o.w = f2bf(y3);
  ((ushort4*)(out + (size_t)row * H_))[tid] = o;
}

extern "C" void kernel_launch(void* const* d_in, const int* in_sizes, int n_in,
                              void* d_out, int out_size, void* d_ws, size_t ws_size,
                              hipStream_t stream) {
  const float* x   = (const float*)d_in[0];
  const float* ipw = (const float*)d_in[1];
  const float* ipb = (const float*)d_in[2];
  const float* opw = (const float*)d_in[3];
  const float* opb = (const float*)d_in[4];
  const float* W1  = (const float*)d_in[5];
  const float* b1  = (const float*)d_in[6];
  const float* lng = (const float*)d_in[7];
  const float* lnb = (const float*)d_in[8];
  const float* W2  = (const float*)d_in[9];
  const float* b2  = (const float*)d_in[10];
  const float* W3  = (const float*)d_in[11];
  const float* b3  = (const float*)d_in[12];
  float* out = (float*)d_out;

  char* p = (char*)d_ws;
  auto take = [&](size_t bytes) { void* q = (void*)p; p += (bytes + 255) & ~(size_t)255; return q; };
  unsigned short* xb  = (unsigned short*)take((size_t)B_ * D_ * 2);
  unsigned short* wvb = (unsigned short*)take((size_t)D_ * D_ * 2);
  unsigned short* wob = (unsigned short*)take((size_t)D_ * D_ * 2);
  unsigned short* w1t = (unsigned short*)take((size_t)M_ * H_ * D_ * 2);
  unsigned short* w2t = (unsigned short*)take((size_t)M_ * H2_ * H_ * 2);
  unsigned short* w3t = (unsigned short*)take((size_t)M_ * D_ * H2_ * 2);
  unsigned short* vb  = (unsigned short*)take((size_t)B_ * D_ * 2);
  unsigned short* ab  = (unsigned short*)take((size_t)B_ * D_ * 2);
  unsigned short* h1p = (unsigned short*)take((size_t)M_ * B_ * H_ * 2);
  unsigned short* h1a = (unsigned short*)take((size_t)M_ * B_ * H_ * 2);
  unsigned short* h2b = (unsigned short*)take((size_t)M_ * B_ * H2_ * 2);

  // --- conversions ---
  cast_f32_bf16<<<dim3((B_ * D_ / 4 + 255) / 256), 256, 0, stream>>>(x, xb, B_ * D_ / 4);
  cast_f32_bf16<<<dim3((D_ * D_ / 4 + 255) / 256), 256, 0, stream>>>(ipw + 2 * D_ * D_, wvb, D_ * D_ / 4);
  cast_f32_bf16<<<dim3((D_ * D_ / 4 + 255) / 256), 256, 0, stream>>>(opw, wob, D_ * D_ / 4);
  transpose_cast<<<dim3(D_ / 32, H_ / 32, M_), dim3(32, 8), 0, stream>>>(W1, w1t, D_, H_);
  transpose_cast<<<dim3(H_ / 32, H2_ / 32, M_), dim3(32, 8), 0, stream>>>(W2, w2t, H_, H2_);
  transpose_cast<<<dim3(H2_ / 32, D_ / 32, M_), dim3(32, 8), 0, stream>>>(W3, w3t, H2_, D_);

  // --- attention (kv_len=1 softmax == 1 -> attn = v) on the 128^2 kernel ---
  gemm_bt<0><<<dim3(B_ / 128, D_ / 128, 1), 256, 0, stream>>>(
      xb, wvb, ipb + 2 * D_, vb, B_, D_, D_, 0, 0, 0, 0);
  gemm_bt<0><<<dim3(B_ / 128, D_ / 128, 1), 256, 0, stream>>>(
      vb, wob, opb, ab, B_, D_, D_, 0, 0, 0, 0);

  // --- 15 mask MLPs on the 256^2 8-phase kernel, batched over grid.z ---
  gemm256<0><<<dim3(B_ / 256, H_ / 256, M_), 512, 0, stream>>>(
      ab, w1t, b1, h1p, H_, D_,
      0, (long)H_ * D_, (long)H_, (long)B_ * H_);
  ln_gelu<<<dim3(B_, M_), 256, 0, stream>>>(h1p, lng, lnb, h1a);
  gemm256<1><<<dim3(B_ / 256, H2_ / 256, M_), 512, 0, stream>>>(
      h1a, w2t, b2, h2b, H2_, H_,
      (long)B_ * H_, (long)H2_ * H_, (long)H2_, (long)B_ * H2_);
  gemm256<2><<<dim3(B_ / 256, D_ / 256, M_), 512, 0, stream>>>(
      h2b, w3t, b3, out, D_, H2_,
      (long)B_ * H2_, (long)D_ * H2_, (long)D_, (long)B_ * D_);
}

// Round 3
// 1622.877 us; speedup vs baseline: 1.0664x; 1.0664x over previous
//
#include <hip/hip_runtime.h>

// Problem constants
#define D_  1024
#define H_  1024
#define H2_ 512
#define M_  15
#define B_  8192

typedef __attribute__((ext_vector_type(4))) float f32x4;
typedef __attribute__((ext_vector_type(8))) short short8;

__device__ __forceinline__ unsigned short f2bf(float f) {
  unsigned int u = __float_as_uint(f);
  u += 0x7fffu + ((u >> 16) & 1u);   // round-to-nearest-even
  return (unsigned short)(u >> 16);
}
__device__ __forceinline__ float bf2f(unsigned int h) {
  return __uint_as_float(h << 16);
}
__device__ __forceinline__ float gelu_exact(float x) {
  return 0.5f * x * (1.0f + erff(x * 0.70710678118654752440f));
}

// ---------------- fp32 -> bf16 cast (vectorized) ----------------
__global__ void cast_f32_bf16(const float* __restrict__ in, unsigned short* __restrict__ out, int n4) {
  int i = blockIdx.x * blockDim.x + threadIdx.x;
  if (i >= n4) return;
  float4 v = ((const float4*)in)[i];
  ushort4 o;
  o.x = f2bf(v.x); o.y = f2bf(v.y); o.z = f2bf(v.z); o.w = f2bf(v.w);
  ((ushort4*)out)[i] = o;
}

// ---------------- fp32 [K,N] -> bf16 [N,K] transpose-cast ----------------
__global__ void transpose_cast(const float* __restrict__ in, unsigned short* __restrict__ out,
                               int K, int N) {
  __shared__ float t[32][33];
  const size_t mo = (size_t)blockIdx.z * K * N;
  in  += mo;
  out += mo;
  const int k0 = blockIdx.x * 32, n0 = blockIdx.y * 32;
  const int tx = threadIdx.x, ty = threadIdx.y;
#pragma unroll
  for (int j = 0; j < 32; j += 8)
    t[ty + j][tx] = in[(size_t)(k0 + ty + j) * N + (n0 + tx)];
  __syncthreads();
#pragma unroll
  for (int j = 0; j < 32; j += 8)
    out[(size_t)(n0 + ty + j) * K + (k0 + tx)] = f2bf(t[tx][ty + j]);
}

// ---------------- 128x128 2-phase GEMM (kept for the small attention GEMMs) -----------
template <int EPI>
__launch_bounds__(256, 3)
__global__ void gemm_bt(const unsigned short* __restrict__ A, const unsigned short* __restrict__ Bt,
                        const float* __restrict__ bias, void* __restrict__ Cout,
                        int Mrows, int N, int K,
                        long sA, long sB, long sBias, long sC) {
  __shared__ __align__(16) unsigned short As[128 * 64];
  __shared__ __align__(16) unsigned short Bs[128 * 64];
  const int mz = blockIdx.z;
  A    += (size_t)mz * sA;
  Bt   += (size_t)mz * sB;
  bias += (size_t)mz * sBias;

  const int tid  = threadIdx.x;
  const int w    = tid >> 6;
  const int lane = tid & 63;
  const int row0 = blockIdx.x * 128;
  const int col0 = blockIdx.y * 128;

  f32x4 acc[4][4];
#pragma unroll
  for (int i = 0; i < 4; ++i)
#pragma unroll
    for (int j = 0; j < 4; ++j) acc[i][j] = (f32x4){0.f, 0.f, 0.f, 0.f};

  const int wm = w >> 1, wn = w & 1;
  const int mrow = lane & 15;
  const int kq   = (lane >> 4) << 3;

  for (int k0 = 0; k0 < K; k0 += 64) {
    __syncthreads();
#pragma unroll
    for (int i = 0; i < 4; ++i) {
      const int c  = i * 256 + tid;
      const int m  = c >> 3;
      const int kk = (c & 7) << 3;
      const unsigned short* gA = A  + (size_t)(row0 + m) * K + (k0 + kk);
      const unsigned short* gB = Bt + (size_t)(col0 + m) * K + (k0 + kk);
      const int ldsoff = (i * 256 + w * 64) * 8;
      __builtin_amdgcn_global_load_lds((const __attribute__((address_space(1))) void*)gA,
                                       (__attribute__((address_space(3))) void*)(As + ldsoff),
                                       16, 0, 0);
      __builtin_amdgcn_global_load_lds((const __attribute__((address_space(1))) void*)gB,
                                       (__attribute__((address_space(3))) void*)(Bs + ldsoff),
                                       16, 0, 0);
    }
    __syncthreads();
#pragma unroll
    for (int ki = 0; ki < 64; ki += 32) {
      short8 af[4], bf[4];
#pragma unroll
      for (int f = 0; f < 4; ++f) {
        af[f] = *(const short8*)(As + (wm * 64 + f * 16 + mrow) * 64 + ki + kq);
        bf[f] = *(const short8*)(Bs + (wn * 64 + f * 16 + mrow) * 64 + ki + kq);
      }
#pragma unroll
      for (int fm = 0; fm < 4; ++fm)
#pragma unroll
        for (int fn = 0; fn < 4; ++fn)
          acc[fm][fn] = __builtin_amdgcn_mfma_f32_16x16x32_bf16(af[fm], bf[fn], acc[fm][fn], 0, 0, 0);
    }
  }

  float*          Cf = (float*)Cout          + (size_t)mz * sC;
  unsigned short* Cb = (unsigned short*)Cout + (size_t)mz * sC;
  const int rq = (lane >> 4) << 2;
  const int cl = lane & 15;
#pragma unroll
  for (int fm = 0; fm < 4; ++fm) {
#pragma unroll
    for (int fn = 0; fn < 4; ++fn) {
      const int cc = col0 + wn * 64 + fn * 16 + cl;
      const float bv = bias[cc];
#pragma unroll
      for (int r = 0; r < 4; ++r) {
        const int rr = row0 + wm * 64 + fm * 16 + rq + r;
        float v = acc[fm][fn][r] + bv;
        if (EPI == 2) {
          Cf[(size_t)rr * N + cc] = 1.0f / (1.0f + __expf(-v));
        } else {
          if (EPI == 1) v = gelu_exact(v);
          Cb[(size_t)rr * N + cc] = f2bf(v);
        }
      }
    }
  }
}

// ============ Persistent 256x256 8-phase counted-vmcnt grouped GEMM ============
// 240 blocks (30 per XCD, bid&7 chunking), each walks tpb output tiles with a
// g-continuous K-tile stream: staging targets g+2/g+3 cross tile boundaries, so
// the pipeline never drains; the epilogue (regs+stores only) overlaps staging.
// Tile decode: by (col) innermost -> concurrent blocks on an XCD share A-panels
// in L2. Schedule/regions/buffers identical to the round-2-verified kernel.
#define BAR()   asm volatile("s_barrier" ::: "memory")
#define LGKM0() asm volatile("s_waitcnt lgkmcnt(0)" ::: "memory")
#define VM6()   asm volatile("s_waitcnt vmcnt(6)" ::: "memory")

// bA/bB include: matrix base + mz*stride + row0(col0)*K + kt*64
#define STG_A(bufi, bA, rho0) do {                                                             \
  _Pragma("unroll")                                                                            \
  for (int j_ = 0; j_ < 2; ++j_) {                                                             \
    const int rho_ = (rho0) + j_ * 64 + (tid >> 3);                                            \
    const int gr_  = (((rho_ >> 6) & 1) << 7) | (((rho_ >> 7) & 1) << 6) | (rho_ & 63);        \
    const unsigned short* g_ = (bA) + (size_t)gr_ * K + (((tid & 7) ^ (rho_ & 7)) << 3);       \
    __builtin_amdgcn_global_load_lds((const __attribute__((address_space(1))) void*)g_,        \
        (__attribute__((address_space(3))) void*)(&As[bufi][(rho0) * 64 + (j_ * 512 + w6 * 64) * 8]), \
        16, 0, 0);                                                                             \
  }                                                                                            \
} while (0)

#define STG_B(bufi, bB, rho0) do {                                                             \
  _Pragma("unroll")                                                                            \
  for (int j_ = 0; j_ < 2; ++j_) {                                                             \
    const int rho_ = (rho0) + j_ * 64 + (tid >> 3);                                            \
    const int gc_  = (((rho_ >> 5) & 3) << 6) | (((rho_ >> 7) & 1) << 5) | (rho_ & 31);        \
    const unsigned short* g_ = (bB) + (size_t)gc_ * K + (((tid & 7) ^ (rho_ & 7)) << 3);       \
    __builtin_amdgcn_global_load_lds((const __attribute__((address_space(1))) void*)g_,        \
        (__attribute__((address_space(3))) void*)(&Bs[bufi][(rho0) * 64 + (j_ * 512 + w6 * 64) * 8]), \
        16, 0, 0);                                                                             \
  }                                                                                            \
} while (0)

#define LDA4(bufi, hi) do {                                                                    \
  _Pragma("unroll")                                                                            \
  for (int q_ = 0; q_ < 4; ++q_) {                                                             \
    const int rho_ = ((hi) ? 128 : 0) + wm * 64 + q_ * 16 + lrow;                              \
    a[q_][0] = *(const short8*)&As[bufi][rho_ * 64 + ((lk ^ (rho_ & 7)) << 3)];                \
    a[q_][1] = *(const short8*)&As[bufi][rho_ * 64 + (((4 + lk) ^ (rho_ & 7)) << 3)];          \
  }                                                                                            \
} while (0)

#define LDB2(bufi, hi) do {                                                                    \
  _Pragma("unroll")                                                                            \
  for (int q_ = 0; q_ < 2; ++q_) {                                                             \
    const int rho_ = ((hi) ? 128 : 0) + wn * 32 + q_ * 16 + lrow;                              \
    b[(hi) * 2 + q_][0] = *(const short8*)&Bs[bufi][rho_ * 64 + ((lk ^ (rho_ & 7)) << 3)];     \
    b[(hi) * 2 + q_][1] = *(const short8*)&Bs[bufi][rho_ * 64 + (((4 + lk) ^ (rho_ & 7)) << 3)]; \
  }                                                                                            \
} while (0)

#define MMQ(mh, nh) do {                                                                       \
  __builtin_amdgcn_s_setprio(1);                                                               \
  _Pragma("unroll")                                                                            \
  for (int mq_ = 0; mq_ < 4; ++mq_) {                                                          \
    _Pragma("unroll")                                                                          \
    for (int nq_ = 0; nq_ < 2; ++nq_) {                                                        \
      acc[(mh) * 4 + mq_][(nh) * 2 + nq_] = __builtin_amdgcn_mfma_f32_16x16x32_bf16(           \
          a[mq_][0], b[(nh) * 2 + nq_][0], acc[(mh) * 4 + mq_][(nh) * 2 + nq_], 0, 0, 0);      \
      acc[(mh) * 4 + mq_][(nh) * 2 + nq_] = __builtin_amdgcn_mfma_f32_16x16x32_bf16(           \
          a[mq_][1], b[(nh) * 2 + nq_][1], acc[(mh) * 4 + mq_][(nh) * 2 + nq_], 0, 0, 0);      \
    }                                                                                          \
  }                                                                                            \
  __builtin_amdgcn_s_setprio(0);                                                               \
} while (0)

// LNT = log2(K/64), LGY = log2(N/256). gx fixed = 32 (B_/256).
template <int EPI, int LNT, int LGY>
__launch_bounds__(512, 2)
__global__ void gemm256p(const unsigned short* __restrict__ A, const unsigned short* __restrict__ Bt,
                         const float* __restrict__ bias, void* __restrict__ Cout,
                         int N, int K, long sA, long sB, long sBias, long sC,
                         int ntiles8, int tpb) {
  __shared__ __align__(16) unsigned short As[2][256 * 64];
  __shared__ __align__(16) unsigned short Bs[2][256 * 64];
  const int NT = 1 << LNT, GYm1 = (1 << LGY) - 1;

  const int bid = blockIdx.x;          // 0..239
  const int xcd = bid & 7, lb = bid >> 3;
  const int cb  = xcd * ntiles8;       // this XCD's tile-chunk base

  const int tid  = threadIdx.x;
  const int w6   = tid >> 6;
  const int lane = tid & 63;
  const int wm   = w6 >> 2;
  const int wn   = w6 & 3;
  const int lrow = lane & 15;
  const int lk   = lane >> 4;

  // current-tile state
  int t_cur = 0;
  int tix  = cb + lb;
  int row0 = ((tix >> LGY) & 31) << 8;
  int col0 = (tix & GYm1) << 8;
  int mz   = tix >> (LGY + 5);
  const unsigned short* bAc = A  + (size_t)mz * sA + (size_t)row0 * K;
  const unsigned short* bBc = Bt + (size_t)mz * sB + (size_t)col0 * K;

  f32x4 acc[8][4];
#pragma unroll
  for (int i = 0; i < 8; ++i)
#pragma unroll
    for (int j = 0; j < 4; ++j) acc[i][j] = (f32x4){0.f, 0.f, 0.f, 0.f};
  short8 a[4][2], b[4][2];

  // prologue: kt0 all 4 regions; kt1 {AP, BR, BS}; wait for kt0 (oldest 8 instrs)
  STG_A(0, bAc, 0); STG_B(0, bBc, 0); STG_B(0, bBc, 128); STG_A(0, bAc, 128);
  STG_A(1, bAc + 64, 0); STG_B(1, bBc + 64, 0); STG_B(1, bBc + 64, 128);
  VM6(); BAR();

  const int totK = tpb << LNT;
#pragma unroll 1
  for (int T = 0; T < totK; T += 2) {
    const int g2 = (T + 2 < totK) ? T + 2 : totK - 1;   // clamped stream targets
    const int g3 = (T + 3 < totK) ? T + 3 : totK - 1;   // (in-bounds re-stage, never read)
    const int t2 = g2 >> LNT, t3 = g3 >> LNT;
    const int tix2 = cb + lb + t2 * 30;
    const int tix3 = cb + lb + t3 * 30;
    const unsigned short* bA2 = A  + (size_t)(tix2 >> (LGY + 5)) * sA
                                   + (size_t)((((tix2 >> LGY) & 31) << 8)) * K + ((g2 & (NT - 1)) << 6);
    const unsigned short* bB2 = Bt + (size_t)(tix2 >> (LGY + 5)) * sB
                                   + (size_t)(((tix2 & GYm1) << 8)) * K + ((g2 & (NT - 1)) << 6);
    const unsigned short* bA3 = A  + (size_t)(tix3 >> (LGY + 5)) * sA
                                   + (size_t)((((tix3 >> LGY) & 31) << 8)) * K + ((g3 & (NT - 1)) << 6);
    const unsigned short* bB3 = Bt + (size_t)(tix3 >> (LGY + 5)) * sB
                                   + (size_t)(((tix3 & GYm1) << 8)) * K + ((g3 & (NT - 1)) << 6);
    const unsigned short* bA1 = bAc + (((T + 1) & (NT - 1)) << 6);   // AQ(T+1), current tile

    // ph1
    LDA4(0, 0); LDB2(0, 0);
    STG_A(1, bA1, 128);
    BAR(); LGKM0(); MMQ(0, 0); BAR();
    // ph2
    LDB2(0, 1);
    STG_A(0, bA2, 0);
    BAR(); LGKM0(); MMQ(0, 1); BAR();
    // ph3
    LDA4(0, 1);
    STG_B(0, bB2, 0);
    BAR(); LGKM0(); MMQ(1, 0); BAR();
    // ph4
    STG_B(0, bB2, 128);
    VM6(); BAR(); MMQ(1, 1); BAR();
    // ph5
    LDA4(1, 0); LDB2(1, 0);
    STG_A(0, bA2, 128);
    BAR(); LGKM0(); MMQ(0, 0); BAR();
    // ph6
    LDB2(1, 1);
    STG_A(1, bA3, 0);
    BAR(); LGKM0(); MMQ(0, 1); BAR();
    // ph7
    LDA4(1, 1);
    STG_B(1, bB3, 0);
    BAR(); LGKM0(); MMQ(1, 0); BAR();
    // ph8
    STG_B(1, bB3, 128);
    VM6(); BAR(); MMQ(1, 1); BAR();

    if (((T + 2) & (NT - 1)) == 0) {
      // ---- epilogue for t_cur (regs + global stores only; pipeline keeps flying) ----
      const float* bp = bias + (size_t)mz * sBias;
      float*          Cf = (float*)Cout          + (size_t)mz * sC;
      unsigned short* Cb = (unsigned short*)Cout + (size_t)mz * sC;
      const int rq = (lane >> 4) << 2;
      const int cl = lane & 15;
#pragma unroll
      for (int nf = 0; nf < 4; ++nf) {
        const int cc = col0 + wn * 64 + nf * 16 + cl;
        const float bv = bp[cc];
#pragma unroll
        for (int mf = 0; mf < 8; ++mf) {
#pragma unroll
          for (int r = 0; r < 4; ++r) {
            const int rr = row0 + wm * 128 + mf * 16 + rq + r;
            float v = acc[mf][nf][r] + bv;
            if (EPI == 2) {
              Cf[(size_t)rr * N + cc] = 1.0f / (1.0f + __expf(-v));
            } else {
              if (EPI == 1) v = gelu_exact(v);
              Cb[(size_t)rr * N + cc] = f2bf(v);
            }
          }
        }
      }
#pragma unroll
      for (int i = 0; i < 8; ++i)
#pragma unroll
        for (int j = 0; j < 4; ++j) acc[i][j] = (f32x4){0.f, 0.f, 0.f, 0.f};
      // ---- advance to next tile ----
      ++t_cur;
      if (t_cur < tpb) {
        tix  = cb + lb + t_cur * 30;
        row0 = ((tix >> LGY) & 31) << 8;
        col0 = (tix & GYm1) << 8;
        mz   = tix >> (LGY + 5);
        bAc  = A  + (size_t)mz * sA + (size_t)row0 * K;
        bBc  = Bt + (size_t)mz * sB + (size_t)col0 * K;
      }
    }
  }
  asm volatile("s_waitcnt vmcnt(0)" ::: "memory");   // drain stray tail prefetches
}

// ---------------- Grouped LayerNorm + exact GELU, rows of length H_ ----------------
__global__ void ln_gelu(const unsigned short* __restrict__ in, const float* __restrict__ g,
                        const float* __restrict__ bb, unsigned short* __restrict__ out) {
  const int m = blockIdx.y;
  in  += (size_t)m * B_ * H_;
  out += (size_t)m * B_ * H_;
  g   += (size_t)m * H_;
  bb  += (size_t)m * H_;
  const int row = blockIdx.x;
  const int tid = threadIdx.x;
  const unsigned short* rp = in + (size_t)row * H_;
  uint2 u = ((const uint2*)rp)[tid];
  float x0 = bf2f(u.x & 0xffffu);
  float x1 = bf2f(u.x >> 16);
  float x2 = bf2f(u.y & 0xffffu);
  float x3 = bf2f(u.y >> 16);

  float s  = x0 + x1 + x2 + x3;
  float s2 = x0 * x0 + x1 * x1 + x2 * x2 + x3 * x3;
#pragma unroll
  for (int o = 32; o > 0; o >>= 1) {
    s  += __shfl_down(s, o);
    s2 += __shfl_down(s2, o);
  }
  __shared__ float red[10];
  const int w = tid >> 6;
  if ((tid & 63) == 0) { red[w] = s; red[4 + w] = s2; }
  __syncthreads();
  if (tid == 0) {
    float ts = red[0] + red[1] + red[2] + red[3];
    float t2 = red[4] + red[5] + red[6] + red[7];
    float mean = ts * (1.0f / H_);
    float var  = t2 * (1.0f / H_) - mean * mean;
    red[8] = mean;
    red[9] = rsqrtf(var + 1e-5f);
  }
  __syncthreads();
  const float mean = red[8], rstd = red[9];
  const int col = tid * 4;
  float y0 = gelu_exact((x0 - mean) * rstd * g[col + 0] + bb[col + 0]);
  float y1 = gelu_exact((x1 - mean) * rstd * g[col + 1] + bb[col + 1]);
  float y2 = gelu_exact((x2 - mean) * rstd * g[col + 2] + bb[col + 2]);
  float y3 = gelu_exact((x3 - mean) * rstd * g[col + 3] + bb[col + 3]);
  ushort4 o;
  o.x = f2bf(y0); o.y = f2bf(y1); o.z = f2bf(y2); o.w = f2bf(y3);
  ((ushort4*)(out + (size_t)row * H_))[tid] = o;
}

extern "C" void kernel_launch(void* const* d_in, const int* in_sizes, int n_in,
                              void* d_out, int out_size, void* d_ws, size_t ws_size,
                              hipStream_t stream) {
  const float* x   = (const float*)d_in[0];
  const float* ipw = (const float*)d_in[1];
  const float* ipb = (const float*)d_in[2];
  const float* opw = (const float*)d_in[3];
  const float* opb = (const float*)d_in[4];
  const float* W1  = (const float*)d_in[5];
  const float* b1  = (const float*)d_in[6];
  const float* lng = (const float*)d_in[7];
  const float* lnb = (const float*)d_in[8];
  const float* W2  = (const float*)d_in[9];
  const float* b2  = (const float*)d_in[10];
  const float* W3  = (const float*)d_in[11];
  const float* b3  = (const float*)d_in[12];
  float* out = (float*)d_out;

  char* p = (char*)d_ws;
  auto take = [&](size_t bytes) { void* q = (void*)p; p += (bytes + 255) & ~(size_t)255; return q; };
  unsigned short* xb  = (unsigned short*)take((size_t)B_ * D_ * 2);
  unsigned short* wvb = (unsigned short*)take((size_t)D_ * D_ * 2);
  unsigned short* wob = (unsigned short*)take((size_t)D_ * D_ * 2);
  unsigned short* w1t = (unsigned short*)take((size_t)M_ * H_ * D_ * 2);
  unsigned short* w2t = (unsigned short*)take((size_t)M_ * H2_ * H_ * 2);
  unsigned short* w3t = (unsigned short*)take((size_t)M_ * D_ * H2_ * 2);
  unsigned short* vb  = (unsigned short*)take((size_t)B_ * D_ * 2);
  unsigned short* ab  = (unsigned short*)take((size_t)B_ * D_ * 2);
  unsigned short* h1p = (unsigned short*)take((size_t)M_ * B_ * H_ * 2);
  unsigned short* h1a = (unsigned short*)take((size_t)M_ * B_ * H_ * 2);
  unsigned short* h2b = (unsigned short*)take((size_t)M_ * B_ * H2_ * 2);

  // --- conversions ---
  cast_f32_bf16<<<dim3((B_ * D_ / 4 + 255) / 256), 256, 0, stream>>>(x, xb, B_ * D_ / 4);
  cast_f32_bf16<<<dim3((D_ * D_ / 4 + 255) / 256), 256, 0, stream>>>(ipw + 2 * D_ * D_, wvb, D_ * D_ / 4);
  cast_f32_bf16<<<dim3((D_ * D_ / 4 + 255) / 256), 256, 0, stream>>>(opw, wob, D_ * D_ / 4);
  transpose_cast<<<dim3(D_ / 32, H_ / 32, M_), dim3(32, 8), 0, stream>>>(W1, w1t, D_, H_);
  transpose_cast<<<dim3(H_ / 32, H2_ / 32, M_), dim3(32, 8), 0, stream>>>(W2, w2t, H_, H2_);
  transpose_cast<<<dim3(H2_ / 32, D_ / 32, M_), dim3(32, 8), 0, stream>>>(W3, w3t, H2_, D_);

  // --- attention (kv_len=1 softmax == 1 -> attn = v) on the 128^2 kernel ---
  gemm_bt<0><<<dim3(B_ / 128, D_ / 128, 1), 256, 0, stream>>>(
      xb, wvb, ipb + 2 * D_, vb, B_, D_, D_, 0, 0, 0, 0);
  gemm_bt<0><<<dim3(B_ / 128, D_ / 128, 1), 256, 0, stream>>>(
      vb, wob, opb, ab, B_, D_, D_, 0, 0, 0, 0);

  // --- 15 mask MLPs on the persistent 256^2 8-phase kernel ---
  // GEMM1: ntiles = 32*4*15 = 1920, tpb = 8; N=1024 (LGY=2), K=1024 (LNT=4)
  gemm256p<0, 4, 2><<<dim3(240), 512, 0, stream>>>(
      ab, w1t, b1, h1p, H_, D_,
      0, (long)H_ * D_, (long)H_, (long)B_ * H_, 1920 / 8, 8);
  ln_gelu<<<dim3(B_, M_), 256, 0, stream>>>(h1p, lng, lnb, h1a);
  // GEMM2: ntiles = 32*2*15 = 960, tpb = 4; N=512 (LGY=1), K=1024 (LNT=4)
  gemm256p<1, 4, 1><<<dim3(240), 512, 0, stream>>>(
      h1a, w2t, b2, h2b, H2_, H_,
      (long)B_ * H_, (long)H2_ * H_, (long)H2_, (long)B_ * H2_, 960 / 8, 4);
  // GEMM3: ntiles = 1920, tpb = 8; N=1024 (LGY=2), K=512 (LNT=3)
  gemm256p<2, 3, 2><<<dim3(240), 512, 0, stream>>>(
      h2b, w3t, b3, out, D_, H2_,
      (long)B_ * H2_, (long)D_ * H2_, (long)D_, (long)B_ * D_, 1920 / 8, 8);
}